// Round 3
// baseline (234.878 us; speedup 1.0000x reference)
//
#include <hip/hip_runtime.h>
#include <math.h>

#define C 1000
#define C4 250   // C/4, row is 4000 B = 250 float4 (16B aligned)

__device__ __forceinline__ float wave_reduce_max(float v) {
#pragma unroll
  for (int off = 32; off > 0; off >>= 1) v = fmaxf(v, __shfl_xor(v, off, 64));
  return v;
}
__device__ __forceinline__ float wave_reduce_sum(float v) {
#pragma unroll
  for (int off = 32; off > 0; off >>= 1) v += __shfl_xor(v, off, 64);
  return v;
}

// Tiled transpose of T (C x C) into At; block (0,0) thread 0 also zeroes the
// scalar result and the done-counter used by reweight_k's fused tail reduce.
__global__ __launch_bounds__(256) void transpose_zero_k(
    const float* __restrict__ A, float* __restrict__ At,
    float* __restrict__ result, unsigned int* __restrict__ done,
    int do_transpose) {
  if (blockIdx.x == 0 && blockIdx.y == 0 && threadIdx.x == 0 && threadIdx.y == 0) {
    *result = 0.0f;
    if (done) *done = 0u;
  }
  if (!do_transpose) return;
  __shared__ float tile[32][33];
  int x = blockIdx.x * 32 + threadIdx.x;
#pragma unroll
  for (int k = 0; k < 32; k += 8) {
    int y = blockIdx.y * 32 + threadIdx.y + k;
    if (x < C && y < C) tile[threadIdx.y + k][threadIdx.x] = A[(size_t)y * C + x];
  }
  __syncthreads();
  int xt = blockIdx.y * 32 + threadIdx.x;
#pragma unroll
  for (int k = 0; k < 32; k += 8) {
    int yt = blockIdx.x * 32 + threadIdx.y + k;
    if (xt < C && yt < C) At[(size_t)yt * C + xt] = tile[threadIdx.x][threadIdx.y + k];
  }
}

// One wave per row, 4 rows per block. beta = e_y / sum_j e_j * T[j,y]
// (softmax normalizer Z cancels between pro1 and pro2);
// ce = log(Z) - (x_y - m).
//
// v3: (a) __launch_bounds__(256,2) gives the allocator 256-VGPR headroom --
//     v2's all-loads-up-front structure spilled t[] at the 28-VGPR default
//     (WRITE_SIZE showed +67 MB of scratch). Same structure, no spill.
//     (b) k=0..2 loads unconditional (lane+128 < 250 always); only k=3 guarded.
//     (c) x_y extracted from registers (select + one shuffle), no scalar load.
//     (d) final reduction fused: last-finished block re-reads partials with
//     agent-scope atomic loads (cross-XCD safe) and sums deterministically.
__global__ __launch_bounds__(256, 2) void reweight_k(
    const float* __restrict__ xin, const int* __restrict__ target,
    const float* __restrict__ Tmat, int tt_mode,
    float* __restrict__ partial, unsigned int* __restrict__ done,
    float* __restrict__ result, int B) {
  int wid = threadIdx.x >> 6;
  int lane = threadIdx.x & 63;
  int row = blockIdx.x * 4 + wid;
  float contrib = 0.0f;
  if (row < B) {
    const float4* x4 = (const float4*)(xin + (size_t)row * C);
    int y = target[row];
    bool has3 = lane < (C4 - 192);   // lane < 58
    if (tt_mode) {
      const float4* t4 = (const float4*)(Tmat + (size_t)y * C);
      // issue all 8 independent 16B loads together (x-row + Tt-row)
      float4 v0 = x4[lane], v1 = x4[lane + 64], v2 = x4[lane + 128];
      float4 t0 = t4[lane], t1 = t4[lane + 64], t2 = t4[lane + 128];
      float4 v3 = make_float4(0.f, 0.f, 0.f, 0.f);
      float4 t3 = make_float4(0.f, 0.f, 0.f, 0.f);
      if (has3) { v3 = x4[lane + 192]; t3 = t4[lane + 192]; }
      float m = fmaxf(fmaxf(fmaxf(v0.x, v0.y), fmaxf(v0.z, v0.w)),
                      fmaxf(fmaxf(v1.x, v1.y), fmaxf(v1.z, v1.w)));
      m = fmaxf(m, fmaxf(fmaxf(v2.x, v2.y), fmaxf(v2.z, v2.w)));
      if (has3) m = fmaxf(m, fmaxf(fmaxf(v3.x, v3.y), fmaxf(v3.z, v3.w)));
      // x_y from registers: owner lane = (y>>2)&63, slot = (y>>2)>>6, comp = y&3
      int jy = y >> 2, cy = y & 3, ky = jy >> 6, ly = jy & 63;
      float4 vv = (ky == 0) ? v0 : (ky == 1) ? v1 : (ky == 2) ? v2 : v3;
      float xc = (cy == 0) ? vv.x : (cy == 1) ? vv.y : (cy == 2) ? vv.z : vv.w;
      float xy = __shfl(xc, ly, 64);
      m = wave_reduce_max(m);
      float se = 0.0f, st = 0.0f;
      {
        float e0 = __expf(v0.x - m), e1 = __expf(v0.y - m);
        float e2 = __expf(v0.z - m), e3 = __expf(v0.w - m);
        se += (e0 + e1) + (e2 + e3);
        st += e0 * t0.x + e1 * t0.y + e2 * t0.z + e3 * t0.w;
      }
      {
        float e0 = __expf(v1.x - m), e1 = __expf(v1.y - m);
        float e2 = __expf(v1.z - m), e3 = __expf(v1.w - m);
        se += (e0 + e1) + (e2 + e3);
        st += e0 * t1.x + e1 * t1.y + e2 * t1.z + e3 * t1.w;
      }
      {
        float e0 = __expf(v2.x - m), e1 = __expf(v2.y - m);
        float e2 = __expf(v2.z - m), e3 = __expf(v2.w - m);
        se += (e0 + e1) + (e2 + e3);
        st += e0 * t2.x + e1 * t2.y + e2 * t2.z + e3 * t2.w;
      }
      if (has3) {
        float e0 = __expf(v3.x - m), e1 = __expf(v3.y - m);
        float e2 = __expf(v3.z - m), e3 = __expf(v3.w - m);
        se += (e0 + e1) + (e2 + e3);
        st += e0 * t3.x + e1 * t3.y + e2 * t3.z + e3 * t3.w;
      }
      se = wave_reduce_sum(se);
      st = wave_reduce_sum(st);
      if (lane == 0) {
        float ey = __expf(xy - m);
        contrib = (ey / st) * (logf(se) - (xy - m));
      }
    } else {
      // fallback: read T columns directly (uncoalesced, L2-cached)
      float4 v[4];
      float m = -INFINITY;
#pragma unroll
      for (int k = 0; k < 4; k++) {
        int j = lane + k * 64;
        if (j < C4) {
          v[k] = x4[j];
          m = fmaxf(m, fmaxf(fmaxf(v[k].x, v[k].y), fmaxf(v[k].z, v[k].w)));
        }
      }
      m = wave_reduce_max(m);
      float se = 0.0f, st = 0.0f;
#pragma unroll
      for (int k = 0; k < 4; k++) {
        int j = lane + k * 64;
        if (j < C4) {
          int jb = j * 4;
          float e0 = __expf(v[k].x - m), e1 = __expf(v[k].y - m);
          float e2 = __expf(v[k].z - m), e3 = __expf(v[k].w - m);
          se += (e0 + e1) + (e2 + e3);
          st += e0 * Tmat[(size_t)(jb + 0) * C + y] +
                e1 * Tmat[(size_t)(jb + 1) * C + y] +
                e2 * Tmat[(size_t)(jb + 2) * C + y] +
                e3 * Tmat[(size_t)(jb + 3) * C + y];
        }
      }
      se = wave_reduce_sum(se);
      st = wave_reduce_sum(st);
      if (lane == 0) {
        float xy = xin[(size_t)row * C + y];
        float ey = __expf(xy - m);
        contrib = (ey / st) * (logf(se) - (xy - m));
      }
    }
  }
  __shared__ float bsum[4];
  __shared__ unsigned int ticket;
  if (lane == 0) bsum[wid] = contrib;
  __syncthreads();
  if (threadIdx.x == 0) {
    float s = (bsum[0] + bsum[1]) + (bsum[2] + bsum[3]);
    if (partial) {
      partial[blockIdx.x] = s;
      __threadfence();                       // device-scope: publish partial
      ticket = atomicAdd(done, 1u);          // device-scope atomic (m20)
    } else {
      atomicAdd(result, s);
    }
  }
  if (!partial) return;
  __syncthreads();
  if (ticket == gridDim.x - 1) {
    // last-finished block: deterministic final reduce (same order as old
    // reduce_k). Agent-scope atomic loads bypass stale per-XCD caches.
    float s = 0.0f;
    for (int i = threadIdx.x; i < (int)gridDim.x; i += 256)
      s += __hip_atomic_load(&partial[i], __ATOMIC_RELAXED,
                             __HIP_MEMORY_SCOPE_AGENT);
    s = wave_reduce_sum(s);
    if (lane == 0) bsum[wid] = s;
    __syncthreads();
    if (threadIdx.x == 0)
      *result = (bsum[0] + bsum[1]) + (bsum[2] + bsum[3]);
  }
}

extern "C" void kernel_launch(void* const* d_in, const int* in_sizes, int n_in,
                              void* d_out, int out_size, void* d_ws, size_t ws_size,
                              hipStream_t stream) {
  const float* xin = (const float*)d_in[0];
  const int* target = (const int*)d_in[1];
  const float* T = (const float*)d_in[2];
  float* result = (float*)d_out;
  int B = in_sizes[1];
  int nblocks = (B + 3) / 4;

  size_t tt_bytes = (size_t)C * C * sizeof(float);   // 4,000,000 B (16B-mult)
  size_t need = tt_bytes + (size_t)(nblocks + 1) * sizeof(float);

  if (ws_size >= need) {
    float* Tt = (float*)d_ws;
    float* partial = (float*)((char*)d_ws + tt_bytes);
    unsigned int* done = (unsigned int*)(partial + nblocks);
    transpose_zero_k<<<dim3(32, 32), dim3(32, 8), 0, stream>>>(T, Tt, result, done, 1);
    reweight_k<<<nblocks, 256, 0, stream>>>(xin, target, Tt, 1, partial, done,
                                            result, B);
  } else {
    // workspace too small: zero result, read T columns directly, atomic combine
    transpose_zero_k<<<dim3(32, 32), dim3(32, 8), 0, stream>>>(T, nullptr, result,
                                                               nullptr, 0);
    reweight_k<<<nblocks, 256, 0, stream>>>(xin, target, T, 0, nullptr, nullptr,
                                            result, B);
  }
}

// Round 4
// 121.444 us; speedup vs baseline: 1.9340x; 1.9340x over previous
//
#include <hip/hip_runtime.h>
#include <math.h>

#define C 1000
#define C4 250   // C/4, row is 4000 B = 250 float4 (16B aligned)

__device__ __forceinline__ float wave_reduce_max(float v) {
#pragma unroll
  for (int off = 32; off > 0; off >>= 1) v = fmaxf(v, __shfl_xor(v, off, 64));
  return v;
}
__device__ __forceinline__ float wave_reduce_sum(float v) {
#pragma unroll
  for (int off = 32; off > 0; off >>= 1) v += __shfl_xor(v, off, 64);
  return v;
}

// Tiled transpose of T (C x C) into At; block (0,0) thread 0 also zeroes the
// scalar result (needed for the atomic fallback path; harmless otherwise).
__global__ __launch_bounds__(256) void transpose_zero_k(
    const float* __restrict__ A, float* __restrict__ At,
    float* __restrict__ result, int do_transpose) {
  if (blockIdx.x == 0 && blockIdx.y == 0 && threadIdx.x == 0 && threadIdx.y == 0)
    *result = 0.0f;
  if (!do_transpose) return;
  __shared__ float tile[32][33];
  int x = blockIdx.x * 32 + threadIdx.x;
#pragma unroll
  for (int k = 0; k < 32; k += 8) {
    int y = blockIdx.y * 32 + threadIdx.y + k;
    if (x < C && y < C) tile[threadIdx.y + k][threadIdx.x] = A[(size_t)y * C + x];
  }
  __syncthreads();
  int xt = blockIdx.y * 32 + threadIdx.x;
#pragma unroll
  for (int k = 0; k < 32; k += 8) {
    int yt = blockIdx.x * 32 + threadIdx.y + k;
    if (xt < C && yt < C) At[(size_t)yt * C + xt] = tile[threadIdx.x][threadIdx.y + k];
  }
}

// One wave per row, 4 rows per block. beta = e_y / sum_j e_j * T[j,y]
// (softmax normalizer Z cancels between pro1 and pro2);
// ce = log(Z) - (x_y - m). Per-block partial sums -> ws (or atomic fallback).
//
// Structure notes from this session's ledger (do NOT re-attempt):
//  - Loading x-row AND Tt-row fragments up-front (8 float4s live) makes the
//    allocator either spill to scratch (+67 MB HBM writes, R2) or serialize
//    all loads at 28 VGPRs (R3). The 2-pass form below (v[] in pass 1, t
//    streamed in pass 2) is what the compiler schedules well.
//  - Cooperative-launch fusion of the 3 kernels halves occupancy and idles
//    on grid.sync (R1: 215 us).
//  - Per-block __threadfence + device-scope ticket for a fused final reduce
//    stalls chip-wide (R3). Keep the separate reduce_k dispatch.
// Only change vs the 106-us baseline: x_y is extracted from the already-live
// v[] registers (selects + one shuffle) instead of a dependent scalar load
// after the reductions. Register-neutral (v[] is live through pass 2 anyway).
__global__ __launch_bounds__(256) void reweight_k(
    const float* __restrict__ xin, const int* __restrict__ target,
    const float* __restrict__ Tmat, int tt_mode,
    float* __restrict__ partial, float* __restrict__ result, int B) {
  int wid = threadIdx.x >> 6;
  int lane = threadIdx.x & 63;
  int row = blockIdx.x * 4 + wid;
  float contrib = 0.0f;
  if (row < B) {
    const float4* x4 = (const float4*)(xin + (size_t)row * C);
    int y = target[row];
    float4 v[4];
    float m = -INFINITY;
#pragma unroll
    for (int k = 0; k < 4; k++) {
      int j = lane + k * 64;
      if (j < C4) {
        v[k] = x4[j];
        m = fmaxf(m, fmaxf(fmaxf(v[k].x, v[k].y), fmaxf(v[k].z, v[k].w)));
      }
    }
    // x_y from registers: owner lane = (y>>2)&63, slot = (y>>2)>>6, comp = y&3.
    // Branchless selects keep v[] statically indexed (no scratch).
    int jy = y >> 2, cy = y & 3, ky = jy >> 6, ly = jy & 63;
    float4 vv = (ky == 0) ? v[0] : (ky == 1) ? v[1] : (ky == 2) ? v[2] : v[3];
    float xc = (cy == 0) ? vv.x : (cy == 1) ? vv.y : (cy == 2) ? vv.z : vv.w;
    float xy = __shfl(xc, ly, 64);
    m = wave_reduce_max(m);
    float se = 0.0f, st = 0.0f;
    if (tt_mode) {
      const float4* t4 = (const float4*)(Tmat + (size_t)y * C);
#pragma unroll
      for (int k = 0; k < 4; k++) {
        int j = lane + k * 64;
        if (j < C4) {
          float4 t = t4[j];
          float e0 = __expf(v[k].x - m), e1 = __expf(v[k].y - m);
          float e2 = __expf(v[k].z - m), e3 = __expf(v[k].w - m);
          se += (e0 + e1) + (e2 + e3);
          st += e0 * t.x + e1 * t.y + e2 * t.z + e3 * t.w;
        }
      }
    } else {
      // fallback: read T columns directly (uncoalesced, L2-cached)
#pragma unroll
      for (int k = 0; k < 4; k++) {
        int j = lane + k * 64;
        if (j < C4) {
          int jb = j * 4;
          float e0 = __expf(v[k].x - m), e1 = __expf(v[k].y - m);
          float e2 = __expf(v[k].z - m), e3 = __expf(v[k].w - m);
          se += (e0 + e1) + (e2 + e3);
          st += e0 * Tmat[(size_t)(jb + 0) * C + y] +
                e1 * Tmat[(size_t)(jb + 1) * C + y] +
                e2 * Tmat[(size_t)(jb + 2) * C + y] +
                e3 * Tmat[(size_t)(jb + 3) * C + y];
        }
      }
    }
    se = wave_reduce_sum(se);
    st = wave_reduce_sum(st);
    if (lane == 0) {
      float ey = __expf(xy - m);
      float ce = logf(se) - (xy - m);
      contrib = (ey / st) * ce;
    }
  }
  __shared__ float bsum[4];
  if (lane == 0) bsum[wid] = contrib;
  __syncthreads();
  if (threadIdx.x == 0) {
    float s = (bsum[0] + bsum[1]) + (bsum[2] + bsum[3]);
    if (partial) partial[blockIdx.x] = s;
    else atomicAdd(result, s);
  }
}

__global__ __launch_bounds__(256) void reduce_k(const float* __restrict__ partial,
                                                float* __restrict__ result, int n) {
  float s = 0.0f;
  for (int i = threadIdx.x; i < n; i += 256) s += partial[i];
  s = wave_reduce_sum(s);
  __shared__ float b[4];
  if ((threadIdx.x & 63) == 0) b[threadIdx.x >> 6] = s;
  __syncthreads();
  if (threadIdx.x == 0) *result = (b[0] + b[1]) + (b[2] + b[3]);
}

extern "C" void kernel_launch(void* const* d_in, const int* in_sizes, int n_in,
                              void* d_out, int out_size, void* d_ws, size_t ws_size,
                              hipStream_t stream) {
  const float* xin = (const float*)d_in[0];
  const int* target = (const int*)d_in[1];
  const float* T = (const float*)d_in[2];
  float* result = (float*)d_out;
  int B = in_sizes[1];
  int nblocks = (B + 3) / 4;

  size_t tt_bytes = (size_t)C * C * sizeof(float);           // 4,000,000 B (16B-mult)
  size_t need = tt_bytes + (size_t)nblocks * sizeof(float);

  if (ws_size >= need) {
    float* Tt = (float*)d_ws;
    float* partial = (float*)((char*)d_ws + tt_bytes);
    transpose_zero_k<<<dim3(32, 32), dim3(32, 8), 0, stream>>>(T, Tt, result, 1);
    reweight_k<<<nblocks, 256, 0, stream>>>(xin, target, Tt, 1, partial, result, B);
    reduce_k<<<1, 256, 0, stream>>>(partial, result, nblocks);
  } else {
    // workspace too small: zero result, read T columns directly, atomic combine
    transpose_zero_k<<<dim3(32, 32), dim3(32, 8), 0, stream>>>(T, nullptr, result, 0);
    reweight_k<<<nblocks, 256, 0, stream>>>(xin, target, T, 0, nullptr, result, B);
  }
}

// Round 5
// 106.464 us; speedup vs baseline: 2.2062x; 1.1407x over previous
//
#include <hip/hip_runtime.h>
#include <math.h>

#define C 1000
#define C4 250   // C/4, row is 4000 B = 250 float4 (16B aligned)

// ---------------------------------------------------------------------------
// SESSION LEDGER (do NOT re-attempt; each was measured slower than this file):
//  R1: cooperative-launch fusion of all 3 kernels (grid.sync) -> 304 us.
//      Occupancy halved, waves idle on cross-XCD sync, VALUBusy 2.7%.
//  R2: x-row + Tt-row loads issued up-front (8 float4 live) -> 137 us.
//      Allocator pinned VGPR_Count=28 and spilled t[] to scratch:
//      WRITE_SIZE +67 MB, reweight_k 48 us.
//  R3: same + __launch_bounds__(256,2) + fused tail reduce via
//      __threadfence/ticket -> 235 us. Allocator STILL chose 28 VGPRs and
//      serialized the loads; per-block device-scope fence stalled chip-wide.
//  R4: x_y extracted from v[] via select-chain + __shfl instead of lane-0
//      scalar load -> 121 us. Select chain constrains scheduling across the
//      max-reduce; the L1-hot scalar load was cheaper.
// Floor arithmetic: harness-fixed ~85-89 us (two 268 MB ws-poison fills at
// ~80% HBM peak + graph overhead) + mandatory traffic ~74 MB ~= 12-16 us.
// This file's kernels measure ~17-22 us total. Addressable margin <= 6 us.
// ---------------------------------------------------------------------------

__device__ __forceinline__ float wave_reduce_max(float v) {
#pragma unroll
  for (int off = 32; off > 0; off >>= 1) v = fmaxf(v, __shfl_xor(v, off, 64));
  return v;
}
__device__ __forceinline__ float wave_reduce_sum(float v) {
#pragma unroll
  for (int off = 32; off > 0; off >>= 1) v += __shfl_xor(v, off, 64);
  return v;
}

// Tiled transpose of T (C x C) into At; block (0,0) thread 0 also zeroes the
// scalar result (needed for the atomic fallback path; harmless otherwise).
__global__ __launch_bounds__(256) void transpose_zero_k(
    const float* __restrict__ A, float* __restrict__ At,
    float* __restrict__ result, int do_transpose) {
  if (blockIdx.x == 0 && blockIdx.y == 0 && threadIdx.x == 0 && threadIdx.y == 0)
    *result = 0.0f;
  if (!do_transpose) return;
  __shared__ float tile[32][33];
  int x = blockIdx.x * 32 + threadIdx.x;
#pragma unroll
  for (int k = 0; k < 32; k += 8) {
    int y = blockIdx.y * 32 + threadIdx.y + k;
    if (x < C && y < C) tile[threadIdx.y + k][threadIdx.x] = A[(size_t)y * C + x];
  }
  __syncthreads();
  int xt = blockIdx.y * 32 + threadIdx.x;
#pragma unroll
  for (int k = 0; k < 32; k += 8) {
    int yt = blockIdx.x * 32 + threadIdx.y + k;
    if (xt < C && yt < C) At[(size_t)yt * C + xt] = tile[threadIdx.x][threadIdx.y + k];
  }
}

// One wave per row, 4 rows per block. beta = e_y / sum_j e_j * T[j,y]
// (softmax normalizer Z cancels between pro1 and pro2);
// ce = log(Z) - (x_y - m). Per-block partial sums -> ws (or atomic fallback).
// 2-pass form (v[] loaded in pass 1, t streamed in pass 2) is what the
// compiler schedules well at its self-chosen 28-32 VGPR budget.
__global__ __launch_bounds__(256) void reweight_k(
    const float* __restrict__ xin, const int* __restrict__ target,
    const float* __restrict__ Tmat, int tt_mode,
    float* __restrict__ partial, float* __restrict__ result, int B) {
  int wid = threadIdx.x >> 6;
  int lane = threadIdx.x & 63;
  int row = blockIdx.x * 4 + wid;
  float contrib = 0.0f;
  if (row < B) {
    const float4* x4 = (const float4*)(xin + (size_t)row * C);
    int y = target[row];
    float4 v[4];
    float m = -INFINITY;
#pragma unroll
    for (int k = 0; k < 4; k++) {
      int j = lane + k * 64;
      if (j < C4) {
        v[k] = x4[j];
        m = fmaxf(m, fmaxf(fmaxf(v[k].x, v[k].y), fmaxf(v[k].z, v[k].w)));
      }
    }
    m = wave_reduce_max(m);
    float se = 0.0f, st = 0.0f;
    if (tt_mode) {
      const float4* t4 = (const float4*)(Tmat + (size_t)y * C);
#pragma unroll
      for (int k = 0; k < 4; k++) {
        int j = lane + k * 64;
        if (j < C4) {
          float4 t = t4[j];
          float e0 = __expf(v[k].x - m), e1 = __expf(v[k].y - m);
          float e2 = __expf(v[k].z - m), e3 = __expf(v[k].w - m);
          se += (e0 + e1) + (e2 + e3);
          st += e0 * t.x + e1 * t.y + e2 * t.z + e3 * t.w;
        }
      }
    } else {
      // fallback: read T columns directly (uncoalesced, L2-cached)
#pragma unroll
      for (int k = 0; k < 4; k++) {
        int j = lane + k * 64;
        if (j < C4) {
          int jb = j * 4;
          float e0 = __expf(v[k].x - m), e1 = __expf(v[k].y - m);
          float e2 = __expf(v[k].z - m), e3 = __expf(v[k].w - m);
          se += (e0 + e1) + (e2 + e3);
          st += e0 * Tmat[(size_t)(jb + 0) * C + y] +
                e1 * Tmat[(size_t)(jb + 1) * C + y] +
                e2 * Tmat[(size_t)(jb + 2) * C + y] +
                e3 * Tmat[(size_t)(jb + 3) * C + y];
        }
      }
    }
    se = wave_reduce_sum(se);
    st = wave_reduce_sum(st);
    if (lane == 0) {
      float xy = xin[(size_t)row * C + y];   // L1-hot, loaded in pass 1
      float ey = __expf(xy - m);
      float ce = logf(se) - (xy - m);
      contrib = (ey / st) * ce;
    }
  }
  __shared__ float bsum[4];
  if (lane == 0) bsum[wid] = contrib;
  __syncthreads();
  if (threadIdx.x == 0) {
    float s = (bsum[0] + bsum[1]) + (bsum[2] + bsum[3]);
    if (partial) partial[blockIdx.x] = s;
    else atomicAdd(result, s);
  }
}

__global__ __launch_bounds__(256) void reduce_k(const float* __restrict__ partial,
                                                float* __restrict__ result, int n) {
  float s = 0.0f;
  for (int i = threadIdx.x; i < n; i += 256) s += partial[i];
  s = wave_reduce_sum(s);
  __shared__ float b[4];
  if ((threadIdx.x & 63) == 0) b[threadIdx.x >> 6] = s;
  __syncthreads();
  if (threadIdx.x == 0) *result = (b[0] + b[1]) + (b[2] + b[3]);
}

extern "C" void kernel_launch(void* const* d_in, const int* in_sizes, int n_in,
                              void* d_out, int out_size, void* d_ws, size_t ws_size,
                              hipStream_t stream) {
  const float* xin = (const float*)d_in[0];
  const int* target = (const int*)d_in[1];
  const float* T = (const float*)d_in[2];
  float* result = (float*)d_out;
  int B = in_sizes[1];
  int nblocks = (B + 3) / 4;

  size_t tt_bytes = (size_t)C * C * sizeof(float);           // 4,000,000 B (16B-mult)
  size_t need = tt_bytes + (size_t)nblocks * sizeof(float);

  if (ws_size >= need) {
    float* Tt = (float*)d_ws;
    float* partial = (float*)((char*)d_ws + tt_bytes);
    transpose_zero_k<<<dim3(32, 32), dim3(32, 8), 0, stream>>>(T, Tt, result, 1);
    reweight_k<<<nblocks, 256, 0, stream>>>(xin, target, Tt, 1, partial, result, B);
    reduce_k<<<1, 256, 0, stream>>>(partial, result, nblocks);
  } else {
    // workspace too small: zero result, read T columns directly, atomic combine
    transpose_zero_k<<<dim3(32, 32), dim3(32, 8), 0, stream>>>(T, nullptr, result, 0);
    reweight_k<<<nblocks, 256, 0, stream>>>(xin, target, T, 0, nullptr, result, B);
  }
}